// Round 15
// baseline (673.700 us; speedup 1.0000x reference)
//
#include <hip/hip_runtime.h>

// ---------------------------------------------------------------------------
// PoetryModel: embed -> x_gates GEMM -> LSTM(128 steps) + streaming classifier
//              (fused, 256 blocks) -> log_softmax epilogue -> out (B,V,S) f32
// B=64 S=128 V=8000 E=256 H=512 G=4H=2048
// ---------------------------------------------------------------------------

using u16   = unsigned short;
using u32   = unsigned int;
using u16x4 = __attribute__((ext_vector_type(4))) u16;
using u16x8 = __attribute__((ext_vector_type(8))) u16;
using bf16x8 = __attribute__((ext_vector_type(8))) __bf16;
using f32x4 = __attribute__((ext_vector_type(4))) float;

#define NB   64        // batch
#define NS   128       // seq len
#define NV   8000      // vocab
#define NVP  8192      // vocab padded to tile
#define NE   256       // embed dim
#define NH   512       // hidden
#define NG   2048      // 4*H
#define NBS  8192      // B*S
#define OUT_BSTRIDE 1024000   // V*S
#define XG_SSTRIDE  131072    // G*B

__device__ inline u16 f2bf(float f) {
    unsigned x = __builtin_bit_cast(unsigned, f);
    unsigned r = (x + 0x7FFFu + ((x >> 16) & 1u)) >> 16;
    return (u16)r;
}
__device__ inline float bf2f(u16 x) {
    u32 u = ((u32)x) << 16;
    return __builtin_bit_cast(float, u);
}

__device__ inline bf16x8 ld_frag(const u16* p) {
    u16x8 v = *(const u16x8*)p;
    return __builtin_bit_cast(bf16x8, v);
}

// LLC-coherent ops: bypass L1+L2, never create/consume dirty L2 lines.
__device__ inline u32 load_llc(const u32* p) {
    u32 v;
    asm volatile("global_load_dword %0, %1, off sc0 sc1\n\t"
                 "s_waitcnt vmcnt(0)"
                 : "=v"(v) : "v"(p) : "memory");
    return v;
}
__device__ inline f32x4 load_llc16(const void* p) {
    f32x4 v;
    asm volatile("global_load_dwordx4 %0, %1, off sc0 sc1\n\t"
                 "s_waitcnt vmcnt(0)"
                 : "=v"(v) : "v"(p) : "memory");
    return v;
}
__device__ inline void store_llc(u32* p, u32 v) {
    asm volatile("global_store_dword %0, %1, off sc0 sc1"
                 :: "v"(p), "v"(v) : "memory");
}
// plain cached load, NO waitcnt: covered by a later vmcnt(0) before use
__device__ inline void prefetch16(f32x4& d, const float* p) {
    asm volatile("global_load_dwordx4 %0, %1, off"
                 : "=v"(d) : "v"(p) : "memory");
}

// direct global->LDS copy, 16B per lane (dst must be wave-uniform base)
__device__ inline void gload_lds16(const u16* g, u16* l) {
    __builtin_amdgcn_global_load_lds(
        (const __attribute__((address_space(1))) unsigned int*)(const void*)g,
        (__attribute__((address_space(3))) unsigned int*)(void*)l,
        16, 0, 0);
}

// 4x4 transpose across lane quad {p} x element {r} (verified round 3)
__device__ inline void quad_transpose(float v[4], int p) {
    float tb[4];
    #pragma unroll
    for (int q2 = 0; q2 < 4; ++q2) tb[q2] = __shfl_xor(v[q2 ^ 2], 2);
    #pragma unroll
    for (int q2 = 0; q2 < 4; ++q2) v[q2] = (((q2 ^ p) & 2) ? tb[q2] : v[q2]);
    #pragma unroll
    for (int q2 = 0; q2 < 4; ++q2) tb[q2] = __shfl_xor(v[q2 ^ 1], 1);
    #pragma unroll
    for (int q2 = 0; q2 < 4; ++q2) v[q2] = (((q2 ^ p) & 1) ? tb[q2] : v[q2]);
}

__device__ inline float lstm_cell(const float v[4], float& c) {
    float i_ = 1.f / (1.f + __expf(-v[0]));
    float f_ = 1.f / (1.f + __expf(-v[1]));
    float e2 = __expf(2.f * v[2]);
    float g_ = 1.f - 2.f / (e2 + 1.f);
    float o_ = 1.f / (1.f + __expf(-v[3]));
    c = f_ * c + i_ * g_;
    float e2c = __expf(2.f * c);
    return o_ * (1.f - 2.f / (e2c + 1.f));
}

// ------------------------------------------------- merged weight converts
__global__ void cvt_all(const float* __restrict__ e,  const float* __restrict__ wi,
                        const float* __restrict__ wh, const float* __restrict__ wc,
                        u16* __restrict__ de,  u16* __restrict__ dwi,
                        u16* __restrict__ dwh, u16* __restrict__ dwc) {
    const int N0 = NV * NE / 8, N1 = NG * NE / 8, N2 = NG * NH / 8, N3 = NV * NH / 8;
    const int total = N0 + N1 + N2 + N3;
    for (int i = blockIdx.x * blockDim.x + threadIdx.x; i < total;
         i += gridDim.x * blockDim.x) {
        const float* s; u16* d; int j;
        if (i < N0)                { s = e;  d = de;  j = i; }
        else if (i < N0 + N1)      { s = wi; d = dwi; j = i - N0; }
        else if (i < N0 + N1 + N2) { s = wh; d = dwh; j = i - N0 - N1; }
        else                       { s = wc; d = dwc; j = i - N0 - N1 - N2; }
        const float4* s4 = (const float4*)s;
        float4 a = s4[2 * j], b = s4[2 * j + 1];
        u16x8 o;
        o[0] = f2bf(a.x); o[1] = f2bf(a.y); o[2] = f2bf(a.z); o[3] = f2bf(a.w);
        o[4] = f2bf(b.x); o[5] = f2bf(b.y); o[6] = f2bf(b.z); o[7] = f2bf(b.w);
        ((u16x8*)d)[j] = o;
    }
}

// ------------------------------------------------- K1: x_gates = x @ W_ih^T
__global__ __launch_bounds__(256) void k1_xgates(
    const u16* __restrict__ Wih, const u16* __restrict__ emb,
    const int* __restrict__ toks,
    const float* __restrict__ bih, const float* __restrict__ bhh,
    float* __restrict__ xg)
{
    __shared__ u16x8 Al8[512];   // [128][32] bf16
    __shared__ u16x8 Bl8[512];
    u16* Al = (u16*)Al8;
    u16* Bl = (u16*)Bl8;

    const int t = threadIdx.x;
    const int lane = t & 63, w = t >> 6;
    const int wm = w >> 1, wn = w & 1;
    const int gtile = blockIdx.y * 128, mtile = blockIdx.x * 128;

    const int r0 = t >> 2, r1 = r0 + 64, q = t & 3;
    const int m0 = mtile + r0, m1 = mtile + r1;
    const int tok0 = toks[(m0 & 63) * NS + (m0 >> 6)];
    const int tok1 = toks[(m1 & 63) * NS + (m1 >> 6)];

    f32x4 acc[4][4];
    for (int i = 0; i < 4; ++i)
        for (int j = 0; j < 4; ++j) acc[i][j] = {0.f, 0.f, 0.f, 0.f};

    const int kc8 = (lane >> 4) * 8;
    for (int kk = 0; kk < 8; ++kk) {
        const int k0 = kk * 32;
        *(u16x8*)&Al[t * 8]         = *(const u16x8*)&Wih[(gtile + r0) * NE + k0 + q * 8];
        *(u16x8*)&Al[(t + 256) * 8] = *(const u16x8*)&Wih[(gtile + r1) * NE + k0 + q * 8];
        *(u16x8*)&Bl[t * 8]         = *(const u16x8*)&emb[tok0 * NE + k0 + q * 8];
        *(u16x8*)&Bl[(t + 256) * 8] = *(const u16x8*)&emb[tok1 * NE + k0 + q * 8];
        __syncthreads();
        bf16x8 af[4], bf[4];
        #pragma unroll
        for (int i = 0; i < 4; ++i) {
            af[i] = ld_frag(&Al[(wm * 64 + i * 16 + (lane & 15)) * 32 + kc8]);
            bf[i] = ld_frag(&Bl[(wn * 64 + i * 16 + (lane & 15)) * 32 + kc8]);
        }
        #pragma unroll
        for (int fi = 0; fi < 4; ++fi)
            #pragma unroll
            for (int fj = 0; fj < 4; ++fj)
                acc[fi][fj] = __builtin_amdgcn_mfma_f32_16x16x32_bf16(
                    af[fi], bf[fj], acc[fi][fj], 0, 0, 0);
        __syncthreads();
    }

    #pragma unroll
    for (int fi = 0; fi < 4; ++fi) {
        const int g0 = gtile + wm * 64 + fi * 16 + ((lane >> 4) << 2);
        const float4 v1 = *(const float4*)&bih[g0];
        const float4 v2 = *(const float4*)&bhh[g0];
        float badd[4] = {v1.x + v2.x, v1.y + v2.y, v1.z + v2.z, v1.w + v2.w};
        #pragma unroll
        for (int fj = 0; fj < 4; ++fj) {
            const int m = mtile + wn * 64 + fj * 16 + (lane & 15);
            const int b = m & 63, s = m >> 6;
            float* dst = &xg[s * XG_SSTRIDE + b];
            #pragma unroll
            for (int r = 0; r < 4; ++r)
                dst[(g0 + r) * 64] = acc[fi][fj][r] + badd[r];
        }
    }
}

// ---------------------------------------- FUSED K2+K3: LSTM + streaming cls
// blocks 0..63: LSTM (R10 code verbatim; hidden stores -> sc0sc1; final flag).
// blocks 64..255: streaming classifier: 4096 tiles = 32 step-quads x 2
// batch-halves x 64 v-tiles; gate on all 64 flags >= 4*qd+5 (hidden(s) is
// LLC-visible before flag(s+2); final flag=1000 covers the tail). R11 MFMA
// layout (4 compute waves), waves 4-7 stage hidden. Poll: 1 wave, sleep(32).
#define LSTM_NBLK 64
#define CLS_NBLK  192
#define NTILES    4096

template <bool STORE_LOGITS>
__global__ __launch_bounds__(512, 2) void k23_fused(
    const u16* __restrict__ Whh,     // [2048][512] bf16
    const float* __restrict__ xg,    // [S][G][B]
    u16* __restrict__ hbuf,          // [2][64][512] bf16 (zeroed)
    u16* __restrict__ hidden,        // [8192][512] bf16
    u32* __restrict__ flags,         // [64] on 128B-strided lines (zeroed)
    const u16* __restrict__ Wc,      // [8192][512] bf16 (padded)
    const float* __restrict__ bcls,
    u16* __restrict__ lgb,           // bf16 logits (bigws only)
    float* __restrict__ lse)
{
    __shared__ __align__(16) u16 hl[16 * 528];     // LSTM h tile
    __shared__ __align__(16) u16 Al[2][4096];      // CLS Wc tiles [128][32]
    __shared__ __align__(16) u16 Bl[2][4096];      // CLS hid tiles
    __shared__ float red[2][128];

    const int t = threadIdx.x, lane = t & 63, w = t >> 6;   // 8 waves

    if (blockIdx.x < LSTM_NBLK) {
        // =================== LSTM role (R10 body) ===================
        const int bg = blockIdx.x >> 3, ug = blockIdx.x & 7;
        const int j = lane & 15;
        const int kc8 = (lane >> 4) * 8;

        const int ubase = ug * 64 + w * 8;
        const int grow0 = (j & 3) * 512 + ubase + (j >> 2);
        const int grow1 = grow0 + 4;

        bf16x8 bw0[16], bw1[16];
        #pragma unroll
        for (int kk = 0; kk < 16; ++kk) {
            bw0[kk] = ld_frag(&Whh[grow0 * NH + kk * 32 + kc8]);
            bw1[kk] = ld_frag(&Whh[grow1 * NH + kk * 32 + kc8]);
        }
        #pragma unroll
        for (int kk = 0; kk < 16; ++kk) {     // pin weights (one-time)
            f32x4 w0 = __builtin_bit_cast(f32x4, bw0[kk]);
            f32x4 w1 = __builtin_bit_cast(f32x4, bw1[kk]);
            asm volatile("" : "+v"(w0), "+v"(w1));
            bw0[kk] = __builtin_bit_cast(bf16x8, w0);
            bw1[kk] = __builtin_bit_cast(bf16x8, w1);
        }

        {
            u16x8 z = {0, 0, 0, 0, 0, 0, 0, 0};
            *(u16x8*)&hl[(8 + (t >> 6)) * 528 + (t & 63) * 8] = z;
        }

        const int srow = t >> 6, scol = (t & 63) * 8;
        const int soff = (bg * 8 + srow) * NH + scol;
        u16* hl_w = &hl[srow * 528 + scol];

        const int p = lane & 3;
        const int q = (lane >> 2) & 3;
        const int batg = bg * 8 + (lane >> 4) * 4 + p;
        const int un0 = ubase + q;
        const bool act = lane < 32;
        const bool sl = act && ((lane & 4) == 0);

        const int xoff0 = grow0 * 64 + bg * 8 + (lane >> 4) * 4;
        const int xoff1 = grow1 * 64 + bg * 8 + (lane >> 4) * 4;

        f32x4 xv0 = {0, 0, 0, 0}, xv1 = {0, 0, 0, 0};
        f32x4 xn0 = {0, 0, 0, 0}, xn1 = {0, 0, 0, 0};
        if (act) {
            xv0 = *(const f32x4*)&xg[xoff0];
            xv1 = *(const f32x4*)&xg[xoff1];
        }
        float cA = 0.f, cB = 0.f;

        for (int step = 0; step < NS; ++step) {
            if (act && step + 1 < NS) {
                const float* xb = &xg[(step + 1) * XG_SSTRIDE];
                prefetch16(xn0, &xb[xoff0]);
                prefetch16(xn1, &xb[xoff1]);
            }
            if (step > 0 && lane < 8) {
                const u32* fp = &flags[(bg * 8 + lane) * 32];
                while ((int)load_llc(fp) < step) __builtin_amdgcn_s_sleep(1);
            }
            {
                f32x4 hv = load_llc16(&hbuf[(step & 1) * (NB * NH) + soff]);
                *(f32x4*)hl_w = hv;
            }
            __syncthreads();

            f32x4 a00 = {0, 0, 0, 0}, a01 = {0, 0, 0, 0};
            f32x4 a10 = {0, 0, 0, 0}, a11 = {0, 0, 0, 0};
            #pragma unroll
            for (int kk = 0; kk < 16; ++kk) {
                bf16x8 av = *(const bf16x8*)&hl[j * 528 + kk * 32 + kc8];
                if (kk & 1) {
                    a01 = __builtin_amdgcn_mfma_f32_16x16x32_bf16(av, bw0[kk], a01, 0, 0, 0);
                    a11 = __builtin_amdgcn_mfma_f32_16x16x32_bf16(av, bw1[kk], a11, 0, 0, 0);
                } else {
                    a00 = __builtin_amdgcn_mfma_f32_16x16x32_bf16(av, bw0[kk], a00, 0, 0, 0);
                    a10 = __builtin_amdgcn_mfma_f32_16x16x32_bf16(av, bw1[kk], a10, 0, 0, 0);
                }
            }

            float v0[4], v1[4];
            #pragma unroll
            for (int r = 0; r < 4; ++r) {
                v0[r] = a00[r] + a01[r] + xv0[r];
                v1[r] = a10[r] + a11[r] + xv1[r];
            }
            quad_transpose(v0, p);
            quad_transpose(v1, p);

            float h0 = lstm_cell(v0, cA);
            float h1 = lstm_cell(v1, cB);
            u32 hb0 = f2bf(h0), hb1 = f2bf(h1);
            u32 o0 = (u32)__shfl_xor((int)hb0, 4);
            u32 o1 = (u32)__shfl_xor((int)hb1, 4);
            u32 pr0 = hb0 | (o0 << 16);
            u32 pr1 = hb1 | (o1 << 16);

            if (sl) {
                u16* hn = hbuf + ((step & 1) ^ 1) * (NB * NH);
                store_llc((u32*)&hn[batg * NH + un0], pr0);
                store_llc((u32*)&hn[batg * NH + un0 + 4], pr1);
            }
            xv0 = xn0; xv1 = xn1;
            __syncthreads();

            if (step + 1 < NS && t == 0)
                store_llc(&flags[blockIdx.x * 32], (u32)(step + 1));

            // hidden history: LLC-coherent so streaming consumers can read
            if (sl) {
                store_llc((u32*)&hidden[(batg * NS + step) * NH + un0], pr0);
                store_llc((u32*)&hidden[(batg * NS + step) * NH + un0 + 4], pr1);
            }
        }
        // final: drain last hidden stores, then signal completion
        asm volatile("s_waitcnt vmcnt(0)" ::: "memory");
        __syncthreads();
        if (t == 0)
            store_llc(&flags[blockIdx.x * 32], 1000u);
        return;
    }

    // =================== streaming classifier role ===================
    const int cid = blockIdx.x - LSTM_NBLK;
    const int sw = w & 3;                       // stage wave 0..3
    const int srow = sw * 16 + (lane >> 2);     // local row 0..63 (issue 0)
    const int scol = (lane & 3) * 8;
    const int kc8 = (lane >> 4) * 8;
    const int wm = w >> 1, wn = w & 1;          // valid for w < 4

    for (int tile = cid; tile < NTILES; tile += CLS_NBLK) {
        const int qd = tile >> 7;               // step quad 0..31
        const int bh = (tile >> 6) & 1;         // batch half
        const int vt = tile & 63;               // v tile
        const int vtile = vt * 128;
        const int s0 = qd * 4;

        // gate: hidden rows for steps s0..s0+3 are LLC-visible
        if (w == 0) {
            const int thr = s0 + 5;
            const u32* fp = &flags[lane * 32];
            while ((int)load_llc(fp) < thr) __builtin_amdgcn_s_sleep(32);
        }
        __syncthreads();

        // per-tile staging sources (k-chunk 0); LDS dsts wave-uniform
        const u16* g0; const u16* g1;
        u16* d0base; u16* d1base;
        if (w < 4) {
            g0 = &Wc[(vtile + srow) * NH + scol];
            g1 = &Wc[(vtile + srow + 64) * NH + scol];
            d0base = &Al[0][(sw * 16) * 32];
            d1base = &Al[0][(sw * 16 + 64) * 32];
        } else {
            const int lr0 = srow, lr1 = srow + 64;
            const int hr0 = (bh * 32 + (lr0 >> 2)) * NS + s0 + (lr0 & 3);
            const int hr1 = (bh * 32 + (lr1 >> 2)) * NS + s0 + (lr1 & 3);
            g0 = &hidden[hr0 * NH + scol];
            g1 = &hidden[hr1 * NH + scol];
            d0base = &Bl[0][(sw * 16) * 32];
            d1base = &Bl[0][(sw * 16 + 64) * 32];
        }

        // prologue: stage k=0 into buffer 0
        gload_lds16(g0, d0base);
        gload_lds16(g1, d1base);
        asm volatile("s_waitcnt vmcnt(0)" ::: "memory");
        __syncthreads();

        f32x4 acc[4][4];
        #pragma unroll
        for (int i = 0; i < 4; ++i)
            #pragma unroll
            for (int j2 = 0; j2 < 4; ++j2) acc[i][j2] = {0.f, 0.f, 0.f, 0.f};

        int cur = 0;
        for (int kk = 0; kk < 16; ++kk) {
            if (kk + 1 < 16) {
                const int k0 = (kk + 1) * 32;
                const int boff = (cur ^ 1) * 4096;
                gload_lds16(g0 + k0, d0base + boff);
                gload_lds16(g1 + k0, d1base + boff);
            }
            if (w < 4) {
                bf16x8 mf[4], vf[4];
                #pragma unroll
                for (int i = 0; i < 4; ++i) {
                    mf[i] = ld_frag(&Bl[cur][(wm * 64 + i * 16 + (lane & 15)) * 32 + kc8]);
                    vf[i] = ld_frag(&Al[cur][(wn * 64 + i * 16 + (lane & 15)) * 32 + kc8]);
                }
                #pragma unroll
                for (int fi = 0; fi < 4; ++fi)
                    #pragma unroll
                    for (int fj = 0; fj < 4; ++fj)
                        acc[fi][fj] = __builtin_amdgcn_mfma_f32_16x16x32_bf16(
                            mf[fi], vf[fj], acc[fi][fj], 0, 0, 0);
            }
            asm volatile("s_waitcnt vmcnt(0)" ::: "memory");
            __syncthreads();
            cur ^= 1;
        }

        // epilogue (compute waves): coalesced u16x4 stores along s + exp sums
        if (w < 4) {
            float lsum[4][4];
            #pragma unroll
            for (int fi = 0; fi < 4; ++fi)
                #pragma unroll
                for (int r = 0; r < 4; ++r) lsum[fi][r] = 0.f;

            #pragma unroll
            for (int fj = 0; fj < 4; ++fj) {
                const int v = vtile + wn * 64 + fj * 16 + (lane & 15);
                const bool vok = (v < NV);
                const float bc = vok ? bcls[v] : 0.f;
                #pragma unroll
                for (int fi = 0; fi < 4; ++fi) {
                    const int lrb = wm * 64 + fi * 16 + ((lane >> 4) << 2);
                    const int b = bh * 32 + (lrb >> 2);
                    float lg[4];
                    #pragma unroll
                    for (int r = 0; r < 4; ++r) {
                        lg[r] = acc[fi][fj][r] + bc;
                        if (vok) lsum[fi][r] += __expf(lg[r]);
                    }
                    if (vok && STORE_LOGITS) {
                        u16x4 o = {f2bf(lg[0]), f2bf(lg[1]), f2bf(lg[2]), f2bf(lg[3])};
                        *(u16x4*)&lgb[b * OUT_BSTRIDE + v * NS + s0] = o;
                    }
                }
            }

            #pragma unroll
            for (int fi = 0; fi < 4; ++fi)
                #pragma unroll
                for (int r = 0; r < 4; ++r) {
                    float sv = lsum[fi][r];
                    sv += __shfl_xor(sv, 1);
                    sv += __shfl_xor(sv, 2);
                    sv += __shfl_xor(sv, 4);
                    sv += __shfl_xor(sv, 8);
                    lsum[fi][r] = sv;
                }
            if ((lane & 15) == 0) {
                #pragma unroll
                for (int fi = 0; fi < 4; ++fi)
                    #pragma unroll
                    for (int r = 0; r < 4; ++r)
                        red[wn][wm * 64 + fi * 16 + ((lane >> 4) << 2) + r] = lsum[fi][r];
            }
        }
        __syncthreads();
        if (t < 128) {
            const int m = (bh * 32 + (t >> 2)) * NS + s0 + (t & 3);
            atomicAdd(&lse[m], red[0][t] + red[1][t]);
        }
    }
}

// ------------------------------------------------------------- epilogues
__global__ void k4_log(const float* __restrict__ lse, float* __restrict__ ll) {
    int i = blockIdx.x * 256 + threadIdx.x;
    if (i < NBS) ll[i] = logf(lse[i]);
}

// bf16-logits path: read u16x4 from ws, write f32 out
__global__ void k5_bf16(float* __restrict__ out, const u16* __restrict__ lgb,
                        const float* __restrict__ ll) {
    const int total4 = NB * NV * NS / 4;
    float4* o4 = (float4*)out;
    const u16x4* l4 = (const u16x4*)lgb;
    for (int i = blockIdx.x * blockDim.x + threadIdx.x; i < total4;
         i += gridDim.x * blockDim.x) {
        const int i4 = i * 4;
        const int b = i4 / OUT_BSTRIDE;
        const int s = i4 & 127;
        u16x4 g = l4[i];
        const float4 l = *(const float4*)&ll[b * NS + s];
        float4 v;
        v.x = bf2f(g[0]) - l.x;
        v.y = bf2f(g[1]) - l.y;
        v.z = bf2f(g[2]) - l.z;
        v.w = bf2f(g[3]) - l.w;
        o4[i] = v;
    }
}

// !bigws fallback: second-pass GEMM writing normalized f32 output directly
__global__ __launch_bounds__(256) void k3_final(
    const u16* __restrict__ Wc, const u16* __restrict__ hid,
    const float* __restrict__ bcls, const float* __restrict__ ll,
    float* __restrict__ out)
{
    __shared__ __align__(16) u16 Al[2][4096];
    __shared__ __align__(16) u16 Bl[2][4096];

    const int t = threadIdx.x;
    const int lane = t & 63, w = t >> 6;
    const int wm = w >> 1, wn = w & 1;
    const int vtile = blockIdx.y * 128, mtile = blockIdx.x * 128;

    const int srow = w * 16 + (lane >> 2);
    const int scol = (lane & 3) * 8;
    const u16* gA = &Wc[(vtile + srow) * NH + scol];
    const u16* gB = &hid[(mtile + srow) * NH + scol];
    const int lo0 = (w * 16) * 32;
    const int lo1 = (w * 16 + 64) * 32;

    f32x4 acc[4][4];
    for (int i = 0; i < 4; ++i)
        for (int j2 = 0; j2 < 4; ++j2) acc[i][j2] = {0.f, 0.f, 0.f, 0.f};

    const int kc8 = (lane >> 4) * 8;
    {
        gload_lds16(gA,           &Al[0][lo0]);
        gload_lds16(gA + 64 * NH, &Al[0][lo1]);
        gload_lds16(gB,           &Bl[0][lo0]);
        gload_lds16(gB + 64 * NH, &Bl[0][lo1]);
        asm volatile("s_waitcnt vmcnt(0)" ::: "memory");
        __syncthreads();
    }
    int cur = 0;
    for (int kk = 0; kk < 16; ++kk) {
        if (kk + 1 < 16) {
            const int k0 = (kk + 1) * 32;
            gload_lds16(gA + k0,           &Al[cur ^ 1][lo0]);
            gload_lds16(gA + 64 * NH + k0, &Al[cur ^ 1][lo1]);
            gload_lds16(gB + k0,           &Bl[cur ^ 1][lo0]);
            gload_lds16(gB + 64 * NH + k0, &Bl[cur ^ 1][lo1]);
        }
        bf16x8 mf[4], vf[4];
        #pragma unroll
        for (int i = 0; i < 4; ++i) {
            mf[i] = ld_frag(&Bl[cur][(wm * 64 + i * 16 + (lane & 15)) * 32 + kc8]);
            vf[i] = ld_frag(&Al[cur][(wn * 64 + i * 16 + (lane & 15)) * 32 + kc8]);
        }
        #pragma unroll
        for (int fi = 0; fi < 4; ++fi)
            #pragma unroll
            for (int fj = 0; fj < 4; ++fj)
                acc[fi][fj] = __builtin_amdgcn_mfma_f32_16x16x32_bf16(
                    mf[fi], vf[fj], acc[fi][fj], 0, 0, 0);
        asm volatile("s_waitcnt vmcnt(0)" ::: "memory");
        __syncthreads();
        cur ^= 1;
    }

    #pragma unroll
    for (int fj = 0; fj < 4; ++fj) {
        const int v = vtile + wn * 64 + fj * 16 + (lane & 15);
        if (v >= NV) continue;
        const float bc = bcls[v];
        #pragma unroll
        for (int fi = 0; fi < 4; ++fi) {
            const int m = mtile + wm * 64 + fi * 16 + ((lane >> 4) << 2);
            const int b = m >> 7, s = m & 127;
            const float4 lv = *(const float4*)&ll[m];
            float4 o;
            o.x = acc[fi][fj][0] + bc - lv.x;
            o.y = acc[fi][fj][1] + bc - lv.y;
            o.z = acc[fi][fj][2] + bc - lv.z;
            o.w = acc[fi][fj][3] + bc - lv.w;
            *(float4*)&out[b * OUT_BSTRIDE + v * NS + s] = o;
        }
    }
}

// ---------------------------------------------------------------------------
extern "C" void kernel_launch(void* const* d_in, const int* in_sizes, int n_in,
                              void* d_out, int out_size, void* d_ws, size_t ws_size,
                              hipStream_t stream) {
    const int*   toks   = (const int*)d_in[0];
    const float* emb_f  = (const float*)d_in[1];
    const float* Wih_f  = (const float*)d_in[2];
    const float* Whh_f  = (const float*)d_in[3];
    const float* bih    = (const float*)d_in[4];
    const float* bhh    = (const float*)d_in[5];
    const float* Wcls_f = (const float*)d_in[6];
    const float* bcls   = (const float*)d_in[7];
    float* out = (float*)d_out;
    char*  ws  = (char*)d_ws;

    // workspace layout (bytes)
    u32*   flags  = (u32*)(ws + 0);            // 8192 (64 x 128B lines)
    float* lse    = (float*)(ws + 8192);       // 32768
    float* loglse = (float*)(ws + 40960);      // 32768
    u16*   hbuf   = (u16*)(ws + 73728);        // 131072 (zeroed: h0 = 0)
    u16*   embb   = (u16*)(ws + 204800);       // 4,096,000
    u16*   wihb   = (u16*)(ws + 4300800);      // 1,048,576
    u16*   whhb   = (u16*)(ws + 5349376);      // 2,097,152
    u16*   wclsb  = (u16*)(ws + 7446528);      // 8,388,608 (padded 8192 rows)
    u16*   hidden = (u16*)(ws + 15835136);     // 8,388,608
    u16*   lgb    = (u16*)(ws + 24223744);     // 131,072,000 (bf16 logits, optional)
    const bool bigws = ws_size >= (size_t)24223744 + (size_t)NB * NV * NS * 2;

    // x_gates f32 [S][G][B] lives in d_out scratch (16.8M floats < 65.5M)
    float* xg = out;

    hipMemsetAsync(ws, 0, 204800, stream);     // flags + lse + loglse + hbuf
    hipMemsetAsync((char*)wclsb + NV * NH * 2, 0, (NVP - NV) * NH * 2, stream);

    cvt_all<<<2048, 256, 0, stream>>>(emb_f, Wih_f, Whh_f, Wcls_f,
                                      embb, wihb, whhb, wclsb);

    k1_xgates<<<dim3(64, 16), 256, 0, stream>>>(wihb, embb, toks, bih, bhh, xg);
    if (bigws) {
        k23_fused<true><<<LSTM_NBLK + CLS_NBLK, 512, 0, stream>>>(
            whhb, xg, hbuf, hidden, flags, wclsb, bcls, lgb, lse);
        k4_log<<<32, 256, 0, stream>>>(lse, loglse);
        k5_bf16<<<2048, 256, 0, stream>>>(out, lgb, loglse);
    } else {
        k23_fused<false><<<LSTM_NBLK + CLS_NBLK, 512, 0, stream>>>(
            whhb, xg, hbuf, hidden, flags, wclsb, bcls, lgb, lse);
        k4_log<<<32, 256, 0, stream>>>(lse, loglse);
        k3_final<<<dim3(64, 64), 256, 0, stream>>>(wclsb, hidden, bcls,
                                                   loglse, out);
    }
}

// Round 16
// 598.995 us; speedup vs baseline: 1.1247x; 1.1247x over previous
//
#include <hip/hip_runtime.h>

// ---------------------------------------------------------------------------
// PoetryModel: embed -> x_gates GEMM -> LSTM(128 steps) -> classifier GEMM
//              -> log_softmax over V -> out (B, V, S) f32
// B=64 S=128 V=8000 E=256 H=512 G=4H=2048
// R16 = byte-identical revert to R14 (session best, 601us). R15's fused
// LSTM+classifier regressed (+72us): consumer LLC traffic inflated the
// LSTM's serial latency chain. Split composition is the measured optimum.
// ---------------------------------------------------------------------------

using u16   = unsigned short;
using u32   = unsigned int;
using u16x4 = __attribute__((ext_vector_type(4))) u16;
using u16x8 = __attribute__((ext_vector_type(8))) u16;
using bf16x8 = __attribute__((ext_vector_type(8))) __bf16;
using f32x4 = __attribute__((ext_vector_type(4))) float;

#define NB   64        // batch
#define NS   128       // seq len
#define NV   8000      // vocab
#define NVP  8192      // vocab padded to tile
#define NE   256       // embed dim
#define NH   512       // hidden
#define NG   2048      // 4*H
#define NBS  8192      // B*S
#define OUT_BSTRIDE 1024000   // V*S
#define XG_SSTRIDE  131072    // G*B

__device__ inline u16 f2bf(float f) {
    unsigned x = __builtin_bit_cast(unsigned, f);
    unsigned r = (x + 0x7FFFu + ((x >> 16) & 1u)) >> 16;
    return (u16)r;
}
__device__ inline float bf2f(u16 x) {
    u32 u = ((u32)x) << 16;
    return __builtin_bit_cast(float, u);
}

__device__ inline bf16x8 ld_frag(const u16* p) {
    u16x8 v = *(const u16x8*)p;
    return __builtin_bit_cast(bf16x8, v);
}

// LLC-coherent ops: bypass L1+L2, never create/consume dirty L2 lines.
__device__ inline u32 load_llc(const u32* p) {
    u32 v;
    asm volatile("global_load_dword %0, %1, off sc0 sc1\n\t"
                 "s_waitcnt vmcnt(0)"
                 : "=v"(v) : "v"(p) : "memory");
    return v;
}
__device__ inline f32x4 load_llc16(const void* p) {
    f32x4 v;
    asm volatile("global_load_dwordx4 %0, %1, off sc0 sc1\n\t"
                 "s_waitcnt vmcnt(0)"
                 : "=v"(v) : "v"(p) : "memory");
    return v;
}
__device__ inline void store_llc(u32* p, u32 v) {
    asm volatile("global_store_dword %0, %1, off sc0 sc1"
                 :: "v"(p), "v"(v) : "memory");
}
// plain cached load, NO waitcnt: covered by a later vmcnt(0) before use
__device__ inline void prefetch16(f32x4& d, const float* p) {
    asm volatile("global_load_dwordx4 %0, %1, off"
                 : "=v"(d) : "v"(p) : "memory");
}

// direct global->LDS copy, 16B per lane (dst must be wave-uniform base)
__device__ inline void gload_lds16(const u16* g, u16* l) {
    __builtin_amdgcn_global_load_lds(
        (const __attribute__((address_space(1))) unsigned int*)(const void*)g,
        (__attribute__((address_space(3))) unsigned int*)(void*)l,
        16, 0, 0);
}

// 4x4 transpose across lane quad {p} x element {r} (verified round 3)
__device__ inline void quad_transpose(float v[4], int p) {
    float tb[4];
    #pragma unroll
    for (int q2 = 0; q2 < 4; ++q2) tb[q2] = __shfl_xor(v[q2 ^ 2], 2);
    #pragma unroll
    for (int q2 = 0; q2 < 4; ++q2) v[q2] = (((q2 ^ p) & 2) ? tb[q2] : v[q2]);
    #pragma unroll
    for (int q2 = 0; q2 < 4; ++q2) tb[q2] = __shfl_xor(v[q2 ^ 1], 1);
    #pragma unroll
    for (int q2 = 0; q2 < 4; ++q2) v[q2] = (((q2 ^ p) & 1) ? tb[q2] : v[q2]);
}

__device__ inline float lstm_cell(const float v[4], float& c) {
    float i_ = 1.f / (1.f + __expf(-v[0]));
    float f_ = 1.f / (1.f + __expf(-v[1]));
    float e2 = __expf(2.f * v[2]);
    float g_ = 1.f - 2.f / (e2 + 1.f);
    float o_ = 1.f / (1.f + __expf(-v[3]));
    c = f_ * c + i_ * g_;
    float e2c = __expf(2.f * c);
    return o_ * (1.f - 2.f / (e2c + 1.f));
}

// ------------------------------------------------- merged weight converts
__global__ void cvt_all(const float* __restrict__ e,  const float* __restrict__ wi,
                        const float* __restrict__ wh, const float* __restrict__ wc,
                        u16* __restrict__ de,  u16* __restrict__ dwi,
                        u16* __restrict__ dwh, u16* __restrict__ dwc) {
    const int N0 = NV * NE / 8, N1 = NG * NE / 8, N2 = NG * NH / 8, N3 = NV * NH / 8;
    const int total = N0 + N1 + N2 + N3;
    for (int i = blockIdx.x * blockDim.x + threadIdx.x; i < total;
         i += gridDim.x * blockDim.x) {
        const float* s; u16* d; int j;
        if (i < N0)                { s = e;  d = de;  j = i; }
        else if (i < N0 + N1)      { s = wi; d = dwi; j = i - N0; }
        else if (i < N0 + N1 + N2) { s = wh; d = dwh; j = i - N0 - N1; }
        else                       { s = wc; d = dwc; j = i - N0 - N1 - N2; }
        const float4* s4 = (const float4*)s;
        float4 a = s4[2 * j], b = s4[2 * j + 1];
        u16x8 o;
        o[0] = f2bf(a.x); o[1] = f2bf(a.y); o[2] = f2bf(a.z); o[3] = f2bf(a.w);
        o[4] = f2bf(b.x); o[5] = f2bf(b.y); o[6] = f2bf(b.z); o[7] = f2bf(b.w);
        ((u16x8*)d)[j] = o;
    }
}

// ------------------------------------------------- K1: x_gates = x @ W_ih^T
__global__ __launch_bounds__(256) void k1_xgates(
    const u16* __restrict__ Wih, const u16* __restrict__ emb,
    const int* __restrict__ toks,
    const float* __restrict__ bih, const float* __restrict__ bhh,
    float* __restrict__ xg)
{
    __shared__ u16x8 Al8[512];   // [128][32] bf16
    __shared__ u16x8 Bl8[512];
    u16* Al = (u16*)Al8;
    u16* Bl = (u16*)Bl8;

    const int t = threadIdx.x;
    const int lane = t & 63, w = t >> 6;
    const int wm = w >> 1, wn = w & 1;
    const int gtile = blockIdx.y * 128, mtile = blockIdx.x * 128;

    const int r0 = t >> 2, r1 = r0 + 64, q = t & 3;
    const int m0 = mtile + r0, m1 = mtile + r1;
    const int tok0 = toks[(m0 & 63) * NS + (m0 >> 6)];
    const int tok1 = toks[(m1 & 63) * NS + (m1 >> 6)];

    f32x4 acc[4][4];
    for (int i = 0; i < 4; ++i)
        for (int j = 0; j < 4; ++j) acc[i][j] = {0.f, 0.f, 0.f, 0.f};

    const int kc8 = (lane >> 4) * 8;
    for (int kk = 0; kk < 8; ++kk) {
        const int k0 = kk * 32;
        *(u16x8*)&Al[t * 8]         = *(const u16x8*)&Wih[(gtile + r0) * NE + k0 + q * 8];
        *(u16x8*)&Al[(t + 256) * 8] = *(const u16x8*)&Wih[(gtile + r1) * NE + k0 + q * 8];
        *(u16x8*)&Bl[t * 8]         = *(const u16x8*)&emb[tok0 * NE + k0 + q * 8];
        *(u16x8*)&Bl[(t + 256) * 8] = *(const u16x8*)&emb[tok1 * NE + k0 + q * 8];
        __syncthreads();
        bf16x8 af[4], bf[4];
        #pragma unroll
        for (int i = 0; i < 4; ++i) {
            af[i] = ld_frag(&Al[(wm * 64 + i * 16 + (lane & 15)) * 32 + kc8]);
            bf[i] = ld_frag(&Bl[(wn * 64 + i * 16 + (lane & 15)) * 32 + kc8]);
        }
        #pragma unroll
        for (int fi = 0; fi < 4; ++fi)
            #pragma unroll
            for (int fj = 0; fj < 4; ++fj)
                acc[fi][fj] = __builtin_amdgcn_mfma_f32_16x16x32_bf16(
                    af[fi], bf[fj], acc[fi][fj], 0, 0, 0);
        __syncthreads();
    }

    #pragma unroll
    for (int fi = 0; fi < 4; ++fi) {
        const int g0 = gtile + wm * 64 + fi * 16 + ((lane >> 4) << 2);
        const float4 v1 = *(const float4*)&bih[g0];
        const float4 v2 = *(const float4*)&bhh[g0];
        float badd[4] = {v1.x + v2.x, v1.y + v2.y, v1.z + v2.z, v1.w + v2.w};
        #pragma unroll
        for (int fj = 0; fj < 4; ++fj) {
            const int m = mtile + wn * 64 + fj * 16 + (lane & 15);
            const int b = m & 63, s = m >> 6;
            float* dst = &xg[s * XG_SSTRIDE + b];
            #pragma unroll
            for (int r = 0; r < 4; ++r)
                dst[(g0 + r) * 64] = acc[fi][fj][r] + badd[r];
        }
    }
}

// --------------------------------------------------------- K2: LSTM (persistent)
// R10/R13 best (364us): byte-identical. 64 blocks = 8 batch-groups x 8
// unit-slices, weights register-resident, 528-stride LDS staging, 8-flag
// group rendezvous at LLC (sc0 sc1), 8 polling lanes/wave, prefetch-first,
// hidden-history after the flag. All protocol deviations tried (R5-R9, R12,
// R15 fusion) regressed — this is the bracketed floor for the structure.
#define LSTM_NBLK 64

__global__ __launch_bounds__(512, 2) void k2_lstm(
    const u16* __restrict__ Whh,     // [2048][512] bf16
    const float* __restrict__ xg,    // [S][G][B]
    u16* __restrict__ hbuf,          // [2][64][512] bf16 (zeroed)
    u16* __restrict__ hidden,        // [8192][512] bf16
    u32* __restrict__ flags)         // [64] on 128B-strided lines (zeroed)
{
    __shared__ __align__(16) u16 hl[16 * 528];   // [16 rows][512+16 pad] bf16

    const int t = threadIdx.x, lane = t & 63, w = t >> 6;   // 8 waves
    const int bg = blockIdx.x >> 3, ug = blockIdx.x & 7;
    const int j = lane & 15;
    const int kc8 = (lane >> 4) * 8;

    const int ubase = ug * 64 + w * 8;
    const int grow0 = (j & 3) * 512 + ubase + (j >> 2);
    const int grow1 = grow0 + 4;

    bf16x8 bw0[16], bw1[16];
    #pragma unroll
    for (int kk = 0; kk < 16; ++kk) {
        bw0[kk] = ld_frag(&Whh[grow0 * NH + kk * 32 + kc8]);
        bw1[kk] = ld_frag(&Whh[grow1 * NH + kk * 32 + kc8]);
    }
    #pragma unroll
    for (int kk = 0; kk < 16; ++kk) {     // pin weights (one-time)
        f32x4 w0 = __builtin_bit_cast(f32x4, bw0[kk]);
        f32x4 w1 = __builtin_bit_cast(f32x4, bw1[kk]);
        asm volatile("" : "+v"(w0), "+v"(w1));
        bw0[kk] = __builtin_bit_cast(bf16x8, w0);
        bw1[kk] = __builtin_bit_cast(bf16x8, w1);
    }

    {
        u16x8 z = {0, 0, 0, 0, 0, 0, 0, 0};
        *(u16x8*)&hl[(8 + (t >> 6)) * 528 + (t & 63) * 8] = z;
    }

    const int srow = t >> 6, scol = (t & 63) * 8;
    const int soff = (bg * 8 + srow) * NH + scol;
    u16* hl_w = &hl[srow * 528 + scol];

    const int p = lane & 3;
    const int q = (lane >> 2) & 3;
    const int batg = bg * 8 + (lane >> 4) * 4 + p;
    const int un0 = ubase + q;
    const bool act = lane < 32;
    const bool sl = act && ((lane & 4) == 0);

    const int xoff0 = grow0 * 64 + bg * 8 + (lane >> 4) * 4;
    const int xoff1 = grow1 * 64 + bg * 8 + (lane >> 4) * 4;

    f32x4 xv0 = {0, 0, 0, 0}, xv1 = {0, 0, 0, 0};
    f32x4 xn0 = {0, 0, 0, 0}, xn1 = {0, 0, 0, 0};
    if (act) {
        xv0 = *(const f32x4*)&xg[xoff0];
        xv1 = *(const f32x4*)&xg[xoff1];
    }
    float cA = 0.f, cB = 0.f;

    for (int step = 0; step < NS; ++step) {
        if (act && step + 1 < NS) {
            const float* xb = &xg[(step + 1) * XG_SSTRIDE];
            prefetch16(xn0, &xb[xoff0]);
            prefetch16(xn1, &xb[xoff1]);
        }
        if (step > 0 && lane < 8) {
            const u32* fp = &flags[(bg * 8 + lane) * 32];
            while ((int)load_llc(fp) < step) __builtin_amdgcn_s_sleep(1);
        }
        {
            f32x4 hv = load_llc16(&hbuf[(step & 1) * (NB * NH) + soff]);
            *(f32x4*)hl_w = hv;
        }
        __syncthreads();

        f32x4 a00 = {0, 0, 0, 0}, a01 = {0, 0, 0, 0};
        f32x4 a10 = {0, 0, 0, 0}, a11 = {0, 0, 0, 0};
        #pragma unroll
        for (int kk = 0; kk < 16; ++kk) {
            bf16x8 av = *(const bf16x8*)&hl[j * 528 + kk * 32 + kc8];
            if (kk & 1) {
                a01 = __builtin_amdgcn_mfma_f32_16x16x32_bf16(av, bw0[kk], a01, 0, 0, 0);
                a11 = __builtin_amdgcn_mfma_f32_16x16x32_bf16(av, bw1[kk], a11, 0, 0, 0);
            } else {
                a00 = __builtin_amdgcn_mfma_f32_16x16x32_bf16(av, bw0[kk], a00, 0, 0, 0);
                a10 = __builtin_amdgcn_mfma_f32_16x16x32_bf16(av, bw1[kk], a10, 0, 0, 0);
            }
        }

        float v0[4], v1[4];
        #pragma unroll
        for (int r = 0; r < 4; ++r) {
            v0[r] = a00[r] + a01[r] + xv0[r];
            v1[r] = a10[r] + a11[r] + xv1[r];
        }
        quad_transpose(v0, p);
        quad_transpose(v1, p);

        float h0 = lstm_cell(v0, cA);
        float h1 = lstm_cell(v1, cB);
        u32 hb0 = f2bf(h0), hb1 = f2bf(h1);
        u32 o0 = (u32)__shfl_xor((int)hb0, 4);
        u32 o1 = (u32)__shfl_xor((int)hb1, 4);
        u32 pr0 = hb0 | (o0 << 16);
        u32 pr1 = hb1 | (o1 << 16);

        if (sl) {
            u16* hn = hbuf + ((step & 1) ^ 1) * (NB * NH);
            store_llc((u32*)&hn[batg * NH + un0], pr0);
            store_llc((u32*)&hn[batg * NH + un0 + 4], pr1);
        }
        xv0 = xn0; xv1 = xn1;
        __syncthreads();

        if (step + 1 < NS && t == 0)
            store_llc(&flags[blockIdx.x * 32], (u32)(step + 1));

        if (sl) {
            *(u32*)&hidden[(batg * NS + step) * NH + un0] = pr0;
            *(u32*)&hidden[(batg * NS + step) * NH + un0 + 4] = pr1;
        }
    }
}

// ------------------------------------- K3: logits = hidden @ W_cls^T + b_cls
// mfma(A=hid, B=Wc) with coalesced stores (R11) + 2-phase double-buffered
// staging (R14): STAGE(k+1) into alternate buffer BEFORE computing tile k;
// single vmcnt(0)+barrier per iteration.
template <bool PACK16>
__global__ __launch_bounds__(256) void k3_cls(
    const u16* __restrict__ Wc, const u16* __restrict__ hid,
    const float* __restrict__ bcls,
    float* __restrict__ outf, u16* __restrict__ outb,
    float* __restrict__ lse)
{
    __shared__ __align__(16) u16 Al[2][128 * 32];   // Wc tiles (v rows), dbuf
    __shared__ __align__(16) u16 Bl[2][128 * 32];   // hid tiles (m rows), dbuf
    __shared__ float red[2][128];

    const int t = threadIdx.x;
    const int lane = t & 63, w = t >> 6;
    const int wm = w >> 1, wn = w & 1;
    const int vtile = blockIdx.y * 128, mtile = blockIdx.x * 128;

    const int srow = w * 16 + (lane >> 2);
    const int scol = (lane & 3) * 8;
    const u16* gA = &Wc[(vtile + srow) * NH + scol];
    const u16* gB = &hid[(mtile + srow) * NH + scol];
    const int lo0 = (w * 16) * 32;        // wave-uniform LDS row-block offsets
    const int lo1 = (w * 16 + 64) * 32;

    f32x4 acc[4][4];
    for (int i = 0; i < 4; ++i)
        for (int j2 = 0; j2 < 4; ++j2) acc[i][j2] = {0.f, 0.f, 0.f, 0.f};

    const int kc8 = (lane >> 4) * 8;

    // prologue: stage tile 0 into buffer 0
    {
        gload_lds16(gA,           &Al[0][lo0]);
        gload_lds16(gA + 64 * NH, &Al[0][lo1]);
        gload_lds16(gB,           &Bl[0][lo0]);
        gload_lds16(gB + 64 * NH, &Bl[0][lo1]);
        asm volatile("s_waitcnt vmcnt(0)" ::: "memory");
        __syncthreads();
    }

    int cur = 0;
    for (int kk = 0; kk < 16; ++kk) {
        // stage tile kk+1 into the alternate buffer (latency hides under MFMA)
        if (kk + 1 < 16) {
            const int k0 = (kk + 1) * 32;
            gload_lds16(gA + k0,           &Al[cur ^ 1][lo0]);
            gload_lds16(gA + 64 * NH + k0, &Al[cur ^ 1][lo1]);
            gload_lds16(gB + k0,           &Bl[cur ^ 1][lo0]);
            gload_lds16(gB + 64 * NH + k0, &Bl[cur ^ 1][lo1]);
        }
        bf16x8 mf[4], vf[4];
        #pragma unroll
        for (int i = 0; i < 4; ++i) {
            mf[i] = ld_frag(&Bl[cur][(wm * 64 + i * 16 + (lane & 15)) * 32 + kc8]);
            vf[i] = ld_frag(&Al[cur][(wn * 64 + i * 16 + (lane & 15)) * 32 + kc8]);
        }
        #pragma unroll
        for (int fi = 0; fi < 4; ++fi)
            #pragma unroll
            for (int fj = 0; fj < 4; ++fj)
                acc[fi][fj] = __builtin_amdgcn_mfma_f32_16x16x32_bf16(
                    mf[fi], vf[fj], acc[fi][fj], 0, 0, 0);
        asm volatile("s_waitcnt vmcnt(0)" ::: "memory");
        __syncthreads();
        cur ^= 1;
    }

    float lsum[4][4];
    #pragma unroll
    for (int fi = 0; fi < 4; ++fi)
        #pragma unroll
        for (int r = 0; r < 4; ++r) lsum[fi][r] = 0.f;

    #pragma unroll
    for (int fj = 0; fj < 4; ++fj) {
        const int v = vtile + wn * 64 + fj * 16 + (lane & 15);
        const bool vok = (v < NV);
        const float bc = vok ? bcls[v] : 0.f;
        #pragma unroll
        for (int fi = 0; fi < 4; ++fi) {
            const int m = mtile + wm * 64 + fi * 16 + ((lane >> 4) << 2);
            const int b = m >> 7, s = m & 127;
            float lg[4];
            #pragma unroll
            for (int r = 0; r < 4; ++r) {
                lg[r] = acc[fi][fj][r] + bc;
                if (vok) lsum[fi][r] += __expf(lg[r]);
            }
            if (vok) {
                if (PACK16) {
                    u16x4 o = {f2bf(lg[0]), f2bf(lg[1]), f2bf(lg[2]), f2bf(lg[3])};
                    *(u16x4*)&outb[b * OUT_BSTRIDE + v * NS + s] = o;
                } else {
                    float4 o = {lg[0], lg[1], lg[2], lg[3]};
                    *(float4*)&outf[b * OUT_BSTRIDE + v * NS + s] = o;
                }
            }
        }
    }

    #pragma unroll
    for (int fi = 0; fi < 4; ++fi)
        #pragma unroll
        for (int r = 0; r < 4; ++r) {
            float sv = lsum[fi][r];
            sv += __shfl_xor(sv, 1);
            sv += __shfl_xor(sv, 2);
            sv += __shfl_xor(sv, 4);
            sv += __shfl_xor(sv, 8);
            lsum[fi][r] = sv;
        }
    if ((lane & 15) == 0) {
        #pragma unroll
        for (int fi = 0; fi < 4; ++fi)
            #pragma unroll
            for (int r = 0; r < 4; ++r)
                red[wn][wm * 64 + fi * 16 + ((lane >> 4) << 2) + r] = lsum[fi][r];
    }
    __syncthreads();
    if (t < 128) {
        const int m = mtile + t;
        atomicAdd(&lse[m], red[0][t] + red[1][t]);
    }
}

// ------------------------------------------------------------- K4/K5 epilogue
__global__ void k4_log(const float* __restrict__ lse, float* __restrict__ ll) {
    int i = blockIdx.x * 256 + threadIdx.x;
    if (i < NBS) ll[i] = logf(lse[i]);
}

// in-place f32 path (fallback)
__global__ void k5_norm(float* __restrict__ out, const float* __restrict__ ll) {
    const int total4 = NB * NV * NS / 4;   // 16,384,000
    float4* o4 = (float4*)out;
    for (int i = blockIdx.x * blockDim.x + threadIdx.x; i < total4;
         i += gridDim.x * blockDim.x) {
        const int i4 = i * 4;
        const int b = i4 / OUT_BSTRIDE;
        const int s = i4 & 127;
        float4 v = o4[i];
        const float4 l = *(const float4*)&ll[b * NS + s];
        v.x -= l.x; v.y -= l.y; v.z -= l.z; v.w -= l.w;
        o4[i] = v;
    }
}

// bf16-logits path: read u16x4 from ws, write f32 out
__global__ void k5_bf16(float* __restrict__ out, const u16* __restrict__ lgb,
                        const float* __restrict__ ll) {
    const int total4 = NB * NV * NS / 4;
    float4* o4 = (float4*)out;
    const u16x4* l4 = (const u16x4*)lgb;
    for (int i = blockIdx.x * blockDim.x + threadIdx.x; i < total4;
         i += gridDim.x * blockDim.x) {
        const int i4 = i * 4;
        const int b = i4 / OUT_BSTRIDE;
        const int s = i4 & 127;
        u16x4 g = l4[i];
        const float4 l = *(const float4*)&ll[b * NS + s];
        float4 v;
        v.x = bf2f(g[0]) - l.x;
        v.y = bf2f(g[1]) - l.y;
        v.z = bf2f(g[2]) - l.z;
        v.w = bf2f(g[3]) - l.w;
        o4[i] = v;
    }
}

// ---------------------------------------------------------------------------
extern "C" void kernel_launch(void* const* d_in, const int* in_sizes, int n_in,
                              void* d_out, int out_size, void* d_ws, size_t ws_size,
                              hipStream_t stream) {
    const int*   toks   = (const int*)d_in[0];
    const float* emb_f  = (const float*)d_in[1];
    const float* Wih_f  = (const float*)d_in[2];
    const float* Whh_f  = (const float*)d_in[3];
    const float* bih    = (const float*)d_in[4];
    const float* bhh    = (const float*)d_in[5];
    const float* Wcls_f = (const float*)d_in[6];
    const float* bcls   = (const float*)d_in[7];
    float* out = (float*)d_out;
    char*  ws  = (char*)d_ws;

    // workspace layout (bytes)
    u32*   flags  = (u32*)(ws + 0);            // 8192 (64 x 128B lines)
    float* lse    = (float*)(ws + 8192);       // 32768
    float* loglse = (float*)(ws + 40960);      // 32768
    u16*   hbuf   = (u16*)(ws + 73728);        // 131072 (zeroed: h0 = 0)
    u16*   embb   = (u16*)(ws + 204800);       // 4,096,000
    u16*   wihb   = (u16*)(ws + 4300800);      // 1,048,576
    u16*   whhb   = (u16*)(ws + 5349376);      // 2,097,152
    u16*   wclsb  = (u16*)(ws + 7446528);      // 8,388,608 (padded 8192 rows)
    u16*   hidden = (u16*)(ws + 15835136);     // 8,388,608
    u16*   lgb    = (u16*)(ws + 24223744);     // 131,072,000 (bf16 logits, optional)
    const bool bigws = ws_size >= (size_t)24223744 + (size_t)NB * NV * NS * 2;

    // x_gates f32 [S][G][B] lives in d_out scratch (16.8M floats < 65.5M)
    float* xg = out;

    hipMemsetAsync(ws, 0, 204800, stream);     // flags + lse + loglse + hbuf
    hipMemsetAsync((char*)wclsb + NV * NH * 2, 0, (NVP - NV) * NH * 2, stream);

    cvt_all<<<2048, 256, 0, stream>>>(emb_f, Wih_f, Whh_f, Wcls_f,
                                      embb, wihb, whhb, wclsb);

    k1_xgates<<<dim3(64, 16), 256, 0, stream>>>(wihb, embb, toks, bih, bhh, xg);
    k2_lstm<<<LSTM_NBLK, 512, 0, stream>>>(whhb, xg, hbuf, hidden, flags);
    if (bigws) {
        k3_cls<true><<<dim3(64, 64), 256, 0, stream>>>(wclsb, hidden, bcls,
                                                       out, lgb, lse);
        k4_log<<<32, 256, 0, stream>>>(lse, loglse);
        k5_bf16<<<2048, 256, 0, stream>>>(out, lgb, loglse);
    } else {
        k3_cls<false><<<dim3(64, 64), 256, 0, stream>>>(wclsb, hidden, bcls,
                                                        out, lgb, lse);
        k4_log<<<32, 256, 0, stream>>>(lse, loglse);
        k5_norm<<<2048, 256, 0, stream>>>(out, loglse);
    }
}